// Round 12
// baseline (578.749 us; speedup 1.0000x reference)
//
#include <hip/hip_runtime.h>
#include <hip/hip_bf16.h>
#include <stdint.h>

// Problem constants (fixed by the reference)
#define N_ 16384
#define M_ 4096
#define D_ 256
#define O_ 256

// Workspace layout (bytes), total ~2.3 MB
#define WS_T    0          // float[N]   exp(sf+ba)   64 KB
#define WS_U    65536      // float[M]   exp(sc)      16 KB
#define WS_R    81920      // float[D]   colsum(Hc)    1 KB
#define WS_WTP  98304      // ushort     Wt packed   128 KB
#define WS_BP   229376     // ushort     Hc packed     2 MB

typedef float  f32x4  __attribute__((ext_vector_type(4)));
typedef short  short8 __attribute__((ext_vector_type(8)));

// fp32 -> bf16 (RNE). Inputs are finite so no NaN handling.
__device__ __forceinline__ unsigned short f2bf(float f) {
  uint32_t u = __float_as_uint(f);
  u += 0x7FFFu + ((u >> 16) & 1u);
  return (unsigned short)(u >> 16);
}
// packed pair fp32 -> bf16
__device__ __forceinline__ uint32_t cvtpk(float a, float b) {
  __hip_bfloat162 h = __float22bfloat162_rn(float2{a, b});
  uint32_t u;
  __builtin_memcpy(&u, &h, 4);
  return u;
}

// ---------------------------------------------------------------------------
// Prep 1: per-row dot with weight vector, then exp(dot + bias).
__global__ __launch_bounds__(256) void rowdot_exp_kernel(
    const float* __restrict__ X, const float* __restrict__ w,
    const float* __restrict__ bias, float* __restrict__ outv) {
  int wv = threadIdx.x >> 6, lane = threadIdx.x & 63;
  int row = blockIdx.x * 4 + wv;
  const float4* x4 = (const float4*)(X + (size_t)row * D_);
  const float4* w4 = (const float4*)w;
  float4 xa = x4[lane], wa4 = w4[lane];
  float s = xa.x * wa4.x + xa.y * wa4.y + xa.z * wa4.z + xa.w * wa4.w;
#pragma unroll
  for (int off = 32; off > 0; off >>= 1) s += __shfl_xor(s, off);
  if (lane == 0) outv[row] = expf(s + (bias ? bias[0] : 0.0f));
}

// ---------------------------------------------------------------------------
// Prep 2: Hc [M,D] fp32 -> BP fragment-major bf16 + colsum.
// k-PERMUTED fragment order: slot j of lane (q,m) = Hc[kg*32 + 4*j + q][cg*16+m].
// (Permutation applied identically to the A-side bit fragments -> contraction
// result unchanged; chosen so __ballot words slice directly into bytes.)
__global__ __launch_bounds__(256) void hc_pack_kernel(
    const float* __restrict__ Hc, unsigned short* __restrict__ BP,
    float* __restrict__ R) {
  __shared__ float tile[64][65];
  __shared__ float red[4][64];
  int bk = blockIdx.x >> 2;   // 64 tiles along M (k)
  int bc = blockIdx.x & 3;    // 4 tiles along D (col)
  int k0 = bk * 64, col0 = bc * 64;
  int t = threadIdx.x;
  int lane = t & 63, wv = t >> 6;
  int m = lane & 15, q = lane >> 4;
  float colsum = 0.0f;
#pragma unroll
  for (int i = 0; i < 16; ++i) {
    int e = t + 256 * i;
    int kk = e >> 6, cc = e & 63;
    float v = Hc[(size_t)(k0 + kk) * D_ + col0 + cc];
    tile[kk][cc] = v;
    colsum += v;
  }
  red[wv][t & 63] = colsum;
  __syncthreads();
  if (t < 64)
    atomicAdd(&R[col0 + t], red[0][t] + red[1][t] + red[2][t] + red[3][t]);
#pragma unroll
  for (int t8 = 0; t8 < 2; ++t8) {
    int tile_id = t8 * 4 + wv;
    int sub = tile_id >> 2, g = tile_id & 3;
    int kgg = bk * 2 + sub;
    int cgg = bc * 4 + g;
    short8 v8;
#pragma unroll
    for (int j = 0; j < 8; ++j)
      v8[j] = (short)f2bf(tile[sub * 32 + 4 * j + q][g * 16 + m]);  // permuted k
    *(short8*)(BP + ((size_t)(kgg * 16 + cgg) * 64 + lane) * 8) = v8;
  }
}

// ---------------------------------------------------------------------------
// Prep 3: Wt [O,D] fp32 -> WtP fragment-major bf16, STANDARD k-order
// (epilogue O-GEMM's A side comes from attn LDS in standard order).
__global__ __launch_bounds__(256) void wt_pack_kernel(
    const float* __restrict__ Wt, unsigned short* __restrict__ WtP) {
  int t = blockIdx.x * 256 + threadIdx.x;    // 0..8191
  int lane = t & 63, cg = (t >> 6) & 15, kg = t >> 10;
  int m = lane & 15, q = lane >> 4;
  const float* src = Wt + (size_t)(cg * 16 + m) * D_ + kg * 32 + q * 8;
  float4 w0 = *(const float4*)src, w1 = *(const float4*)(src + 4);
  short8 v8;
  v8[0] = (short)f2bf(w0.x); v8[1] = (short)f2bf(w0.y);
  v8[2] = (short)f2bf(w0.z); v8[3] = (short)f2bf(w0.w);
  v8[4] = (short)f2bf(w1.x); v8[5] = (short)f2bf(w1.y);
  v8[6] = (short)f2bf(w1.z); v8[7] = (short)f2bf(w1.w);
  *(short8*)(WtP + (size_t)t * 8) = v8;
}

// ---------------------------------------------------------------------------
// A-fragment from 8 bits (permuted order): slot j = bit_j ? (t*u8[j] - 1) : 0.
// u8[j] = u[kg*32 + 4*j + q] supplied by caller. bf16 0x0000 = exact +0.
__device__ __forceinline__ short8 frag_from(uint32_t bits, float t,
                                            const float u8[8]) {
  union { short8 s; uint32_t u[4]; } r;
#pragma unroll
  for (int p = 0; p < 4; ++p) {
    float cl = fmaf(t, u8[2 * p], -1.0f);
    float ch = fmaf(t, u8[2 * p + 1], -1.0f);
    uint32_t mlo = 0u - ((bits >> (2 * p)) & 1u);      // 0 or ~0
    uint32_t mhi = 0u - ((bits >> (2 * p + 1)) & 1u);
    r.u[p] = cvtpk(cl, ch) & ((mlo & 0x0000FFFFu) | (mhi & 0xFFFF0000u));
  }
  return r.s;
}

// ---------------------------------------------------------------------------
// MEGA: one kernel = pack bits (adj read once, row-contiguous) + GEMM + epilogue.
// Block = 64 rows x 256 cols x full K, 1024 thr = 16 waves. Grid = N/64 = 256
// -> exactly 1 block/CU (LDS ~116 KB, VGPR capped 128 by launch_bounds).
// Phase 1: wave w streams rows 4w..4w+3 (float4/lane contiguous, depth-1 chunk
//   prefetch -> 4 KB/wave in flight); __ballot packs bits; bit l of u64 word
//   (r, chunk*4+c) = adj[r][chunk*256+4l+c]; byte t of that word = kstep
//   kg=chunk*8+t, quad q=c, slots j=0..7 (matches BP's 4j+q permutation).
//   Exact row denoms t_r*sum(adj*u)-sum(adj) reduced in-wave -> registers.
// Phase 2: R11 K-loop: 4 row-tiles x 4 colq x ksub quarter; bits+u from LDS,
//   B from BP (L2) with depth-1 register prefetch; barrier-free 32 iters.
// Phase 3: LDS fp32 atomic combine (4 adds/addr), attn=(C+R)/(L+M)+Hf ->
//   LDS bf16 (overlays bits+u), O-GEMM vs WtP, relu, out.
__global__ __launch_bounds__(1024, 4) void mega_kernel(
    const float* __restrict__ adj, const unsigned short* __restrict__ BP,
    const float* __restrict__ tv, const float* __restrict__ uv,
    const float* __restrict__ Rv, const float* __restrict__ Hf,
    const unsigned short* __restrict__ WtP, const float* __restrict__ bt,
    float* __restrict__ out) {
  union SM {
    struct {
      unsigned long long bt64[64][65];  // 33.3 KB  (+1 u64 pad per row)
      float u[M_];                      // 16 KB
    } s;
    unsigned short attn[64][264];       // 33.8 KB (aliases bits after K loop)
  };
  __shared__ SM sm;
  __shared__ float part[64][260];       // 66.6 KB fp32 C accumulator

  int tid = threadIdx.x;
  int w = tid >> 6, lane = tid & 63;
  int q = lane >> 4, m = lane & 15;
  int colq = w >> 2, ksub = w & 3;
  int i0 = blockIdx.x * 64;

  // ---- pre-barrier staging (no LDS deps): B prefetch, t's, Rv, adj chunk 0
  const unsigned short* bbase = BP + (size_t)(colq * 4) * 512 + (size_t)lane * 8;
  int kg0 = ksub * 32;
  short8 curB[4];
#pragma unroll
  for (int n = 0; n < 4; ++n)
    curB[n] = *(const short8*)(bbase + ((size_t)kg0 * 16 + n) * 512);
  float t0 = tv[i0 + m], t1 = tv[i0 + 16 + m];
  float t2 = tv[i0 + 32 + m], t3 = tv[i0 + 48 + m];
  float4 rvv = *(const float4*)(Rv + lane * 4);

  int r0 = w * 4;                                // phase-1 rows of this wave
  const float* ar = adj + (size_t)(i0 + r0) * M_ + lane * 4;
  float tva = tv[i0 + r0], tvb = tv[i0 + r0 + 1];
  float tvc = tv[i0 + r0 + 2], tvd = tv[i0 + r0 + 3];
  float4 v0 = *(const float4*)(ar);
  float4 v1 = *(const float4*)(ar + M_);
  float4 v2 = *(const float4*)(ar + 2 * M_);
  float4 v3 = *(const float4*)(ar + 3 * M_);

  for (int i = tid; i < M_; i += 1024) sm.s.u[i] = uv[i];
  {
    float* pz = &part[0][0];
    for (int i = tid; i < 64 * 260; i += 1024) pz[i] = 0.0f;
  }
  __syncthreads();  // u + part-zero ready

  // ---- Phase 1: pack bits + denominators
  float su0 = 0.f, sc0 = 0.f, su1 = 0.f, sc1 = 0.f;
  float su2 = 0.f, sc2 = 0.f, su3 = 0.f, sc3 = 0.f;
  const float4* u4 = (const float4*)sm.s.u;
#pragma unroll 1
  for (int chunk = 0; chunk < 16; ++chunk) {
    int nx = (chunk + 1 < 16) ? (chunk + 1) * 256 : 0;   // wrap: harmless reload
    float4 n0 = *(const float4*)(ar + nx);
    float4 n1 = *(const float4*)(ar + nx + M_);
    float4 n2 = *(const float4*)(ar + nx + 2 * M_);
    float4 n3 = *(const float4*)(ar + nx + 3 * M_);
    float4 uu = u4[chunk * 64 + lane];

    unsigned long long b00 = __ballot(v0.x != 0.f), b01 = __ballot(v0.y != 0.f);
    unsigned long long b02 = __ballot(v0.z != 0.f), b03 = __ballot(v0.w != 0.f);
    unsigned long long b10 = __ballot(v1.x != 0.f), b11 = __ballot(v1.y != 0.f);
    unsigned long long b12 = __ballot(v1.z != 0.f), b13 = __ballot(v1.w != 0.f);
    unsigned long long b20 = __ballot(v2.x != 0.f), b21 = __ballot(v2.y != 0.f);
    unsigned long long b22 = __ballot(v2.z != 0.f), b23 = __ballot(v2.w != 0.f);
    unsigned long long b30 = __ballot(v3.x != 0.f), b31 = __ballot(v3.y != 0.f);
    unsigned long long b32 = __ballot(v3.z != 0.f), b33 = __ballot(v3.w != 0.f);
    su0 += v0.x * uu.x + v0.y * uu.y + v0.z * uu.z + v0.w * uu.w;
    sc0 += (v0.x + v0.y) + (v0.z + v0.w);
    su1 += v1.x * uu.x + v1.y * uu.y + v1.z * uu.z + v1.w * uu.w;
    sc1 += (v1.x + v1.y) + (v1.z + v1.w);
    su2 += v2.x * uu.x + v2.y * uu.y + v2.z * uu.z + v2.w * uu.w;
    sc2 += (v2.x + v2.y) + (v2.z + v2.w);
    su3 += v3.x * uu.x + v3.y * uu.y + v3.z * uu.z + v3.w * uu.w;
    sc3 += (v3.x + v3.y) + (v3.z + v3.w);

    // 16 wave-uniform u64s -> lanes 0..15 via select tree (rr = lane>>2, c = lane&3)
#define SELC(a, b, c_, d) ((lane & 2) ? ((lane & 1) ? (d) : (c_)) : ((lane & 1) ? (b) : (a)))
    unsigned long long rs0 = SELC(b00, b01, b02, b03);
    unsigned long long rs1 = SELC(b10, b11, b12, b13);
    unsigned long long rs2 = SELC(b20, b21, b22, b23);
    unsigned long long rs3 = SELC(b30, b31, b32, b33);
#undef SELC
    unsigned long long val =
        (lane & 8) ? ((lane & 4) ? rs3 : rs2) : ((lane & 4) ? rs1 : rs0);
    if (lane < 16)
      sm.s.bt64[r0 + (lane >> 2)][chunk * 4 + (lane & 3)] = val;

    v0 = n0; v1 = n1; v2 = n2; v3 = n3;
  }
  // in-wave reduce -> wave-uniform denominators for rows r0..r0+3
#pragma unroll
  for (int off = 32; off > 0; off >>= 1) {
    su0 += __shfl_xor(su0, off); sc0 += __shfl_xor(sc0, off);
    su1 += __shfl_xor(su1, off); sc1 += __shfl_xor(sc1, off);
    su2 += __shfl_xor(su2, off); sc2 += __shfl_xor(sc2, off);
    su3 += __shfl_xor(su3, off); sc3 += __shfl_xor(sc3, off);
  }
  float invL0 = 1.0f / (tva * su0 - sc0 + (float)M_);
  float invL1 = 1.0f / (tvb * su1 - sc1 + (float)M_);
  float invL2 = 1.0f / (tvc * su2 - sc2 + (float)M_);
  float invL3 = 1.0f / (tvd * su3 - sc3 + (float)M_);
  __syncthreads();  // all bits ready

  // ---- Phase 2: barrier-free K loop (32 ksteps of this wave's K quarter)
  const uint32_t* bt32 = (const uint32_t*)&sm.s.bt64[0][0];   // row stride 130
  f32x4 acc[4][4];
#pragma unroll
  for (int s = 0; s < 4; ++s)
#pragma unroll
    for (int n = 0; n < 4; ++n) acc[s][n] = (f32x4){0.f, 0.f, 0.f, 0.f};
  uint32_t w0 = 0, w1 = 0, w2 = 0, w3 = 0;

#pragma unroll 4
  for (int it = 0; it < 32; ++it) {
    int kg = kg0 + it;
    int kn = (it + 1 < 32) ? kg + 1 : kg0;   // wrap: harmless reload
    short8 nB[4];
#pragma unroll
    for (int n = 0; n < 4; ++n)
      nB[n] = *(const short8*)(bbase + ((size_t)kn * 16 + n) * 512);
    if ((it & 3) == 0) {                      // one u32 covers 4 ksteps
      int widx = (kg >> 3) * 8 + 2 * q + ((kg & 7) >> 2);
      w0 = bt32[(size_t)m * 130 + widx];
      w1 = bt32[(size_t)(16 + m) * 130 + widx];
      w2 = bt32[(size_t)(32 + m) * 130 + widx];
      w3 = bt32[(size_t)(48 + m) * 130 + widx];
    }
    int sh = (kg & 3) * 8;
    float u8[8];
    const float* up = &sm.s.u[kg * 32 + q];
#pragma unroll
    for (int j = 0; j < 8; ++j) u8[j] = up[4 * j];
    short8 af0 = frag_from((w0 >> sh) & 0xffu, t0, u8);
    short8 af1 = frag_from((w1 >> sh) & 0xffu, t1, u8);
    short8 af2 = frag_from((w2 >> sh) & 0xffu, t2, u8);
    short8 af3 = frag_from((w3 >> sh) & 0xffu, t3, u8);
#pragma unroll
    for (int n = 0; n < 4; ++n) {
      acc[0][n] = __builtin_amdgcn_mfma_f32_16x16x32_bf16(af0, curB[n], acc[0][n], 0, 0, 0);
      acc[1][n] = __builtin_amdgcn_mfma_f32_16x16x32_bf16(af1, curB[n], acc[1][n], 0, 0, 0);
      acc[2][n] = __builtin_amdgcn_mfma_f32_16x16x32_bf16(af2, curB[n], acc[2][n], 0, 0, 0);
      acc[3][n] = __builtin_amdgcn_mfma_f32_16x16x32_bf16(af3, curB[n], acc[3][n], 0, 0, 0);
    }
#pragma unroll
    for (int n = 0; n < 4; ++n) curB[n] = nB[n];
  }

  // ---- Phase 3: combine K-quarter partials in LDS (4 adds/address)
#pragma unroll
  for (int s = 0; s < 4; ++s)
#pragma unroll
    for (int n = 0; n < 4; ++n) {
      int col = colq * 64 + n * 16 + m;
#pragma unroll
      for (int r = 0; r < 4; ++r)
        atomicAdd(&part[s * 16 + q * 4 + r][col], acc[s][n][r]);  // C/D: row=(lane>>4)*4+reg
    }
  __syncthreads();

  // attn = (C + R)/(L + M) + Hf -> bf16 LDS (overlays bits+u, both dead)
#pragma unroll
  for (int rr = 0; rr < 4; ++rr) {
    int r = r0 + rr;
    float invL = rr == 0 ? invL0 : rr == 1 ? invL1 : rr == 2 ? invL2 : invL3;
    float4 pv = *(const float4*)&part[r][lane * 4];
    float4 hv = *(const float4*)(Hf + (size_t)(i0 + r) * D_ + lane * 4);
    float a0 = fmaf(pv.x + rvv.x, invL, hv.x);
    float a1 = fmaf(pv.y + rvv.y, invL, hv.y);
    float a2 = fmaf(pv.z + rvv.z, invL, hv.z);
    float a3 = fmaf(pv.w + rvv.w, invL, hv.w);
    *(uint32_t*)&sm.attn[r][lane * 4] = cvtpk(a0, a1);
    *(uint32_t*)&sm.attn[r][lane * 4 + 2] = cvtpk(a2, a3);
  }
  __syncthreads();

  // O-GEMM: out = relu(attn @ Wt^T + bt). 16 waves = 4 rtiles x 4 col-64s.
  int rtile = w & 3, c64 = w >> 2;
  f32x4 facc[4];
#pragma unroll
  for (int n = 0; n < 4; ++n) facc[n] = (f32x4){0.f, 0.f, 0.f, 0.f};
#pragma unroll
  for (int kf = 0; kf < 8; ++kf) {
    short8 af = *(const short8*)&sm.attn[rtile * 16 + m][kf * 32 + q * 8];
#pragma unroll
    for (int n = 0; n < 4; ++n) {
      int cg = c64 * 4 + n;
      short8 bf = *(const short8*)(WtP + ((size_t)(kf * 16 + cg) * 64 + lane) * 8);
      facc[n] = __builtin_amdgcn_mfma_f32_16x16x32_bf16(af, bf, facc[n], 0, 0, 0);
    }
  }
#pragma unroll
  for (int n = 0; n < 4; ++n) {
    int col = c64 * 64 + n * 16 + m;
    float b = bt[col];
#pragma unroll
    for (int r = 0; r < 4; ++r) {
      size_t row = (size_t)i0 + rtile * 16 + q * 4 + r;
      out[row * O_ + col] = fmaxf(facc[n][r] + b, 0.0f);
    }
  }
}

// ---------------------------------------------------------------------------
extern "C" void kernel_launch(void* const* d_in, const int* in_sizes, int n_in,
                              void* d_out, int out_size, void* d_ws, size_t ws_size,
                              hipStream_t stream) {
  const float* Hf  = (const float*)d_in[0];  // [N,D]
  const float* Hc  = (const float*)d_in[1];  // [M,D]
  const float* adj = (const float*)d_in[2];  // [N,M]
  const float* wa  = (const float*)d_in[3];  // [2D]
  const float* ba  = (const float*)d_in[4];  // [1]
  const float* Wt  = (const float*)d_in[5];  // [O,D]
  const float* bt  = (const float*)d_in[6];  // [O]
  float* out = (float*)d_out;

  char* ws = (char*)d_ws;
  float* tv = (float*)(ws + WS_T);
  float* uv = (float*)(ws + WS_U);
  float* Rv = (float*)(ws + WS_R);
  unsigned short* WtP = (unsigned short*)(ws + WS_WTP);
  unsigned short* BP  = (unsigned short*)(ws + WS_BP);

  hipMemsetAsync(Rv, 0, D_ * sizeof(float), stream);  // atomic target

  rowdot_exp_kernel<<<N_ / 4, 256, 0, stream>>>(Hf, wa, ba, tv);           // t = exp(sf+ba)
  rowdot_exp_kernel<<<M_ / 4, 256, 0, stream>>>(Hc, wa + D_, nullptr, uv); // u = exp(sc)
  hc_pack_kernel<<<256, 256, 0, stream>>>(Hc, BP, Rv);
  wt_pack_kernel<<<32, 256, 0, stream>>>(Wt, WtP);

  mega_kernel<<<N_ / 64, 1024, 0, stream>>>(adj, BP, tv, uv, Rv, Hf, WtP, bt, out);
}

// Round 13
// 578.575 us; speedup vs baseline: 1.0003x; 1.0003x over previous
//
#include <hip/hip_runtime.h>
#include <hip/hip_bf16.h>
#include <stdint.h>

// Problem constants (fixed by the reference)
#define N_ 16384
#define M_ 4096
#define D_ 256
#define O_ 256

// Workspace layout (bytes), total ~2.3 MB
#define WS_T    0          // float[N]   exp(sf+ba)   64 KB
#define WS_U    65536      // float[M]   exp(sc)      16 KB
#define WS_R    81920      // float[D]   colsum(Hc)    1 KB
#define WS_WTP  98304      // ushort     Wt packed   128 KB
#define WS_BP   229376     // ushort     Hc packed     2 MB

typedef float  f32x4  __attribute__((ext_vector_type(4)));
typedef short  short8 __attribute__((ext_vector_type(8)));

// fp32 -> bf16 (RNE). Inputs are finite so no NaN handling.
__device__ __forceinline__ unsigned short f2bf(float f) {
  uint32_t u = __float_as_uint(f);
  u += 0x7FFFu + ((u >> 16) & 1u);
  return (unsigned short)(u >> 16);
}
// packed pair fp32 -> bf16
__device__ __forceinline__ uint32_t cvtpk(float a, float b) {
  __hip_bfloat162 h = __float22bfloat162_rn(float2{a, b});
  uint32_t u;
  __builtin_memcpy(&u, &h, 4);
  return u;
}

// ---------------------------------------------------------------------------
// Prep 1: per-row dot with weight vector, then exp(dot + bias).
__global__ __launch_bounds__(256) void rowdot_exp_kernel(
    const float* __restrict__ X, const float* __restrict__ w,
    const float* __restrict__ bias, float* __restrict__ outv) {
  int wv = threadIdx.x >> 6, lane = threadIdx.x & 63;
  int row = blockIdx.x * 4 + wv;
  const float4* x4 = (const float4*)(X + (size_t)row * D_);
  const float4* w4 = (const float4*)w;
  float4 xa = x4[lane], wa4 = w4[lane];
  float s = xa.x * wa4.x + xa.y * wa4.y + xa.z * wa4.z + xa.w * wa4.w;
#pragma unroll
  for (int off = 32; off > 0; off >>= 1) s += __shfl_xor(s, off);
  if (lane == 0) outv[row] = expf(s + (bias ? bias[0] : 0.0f));
}

// ---------------------------------------------------------------------------
// Prep 2: Hc [M,D] fp32 -> BP fragment-major bf16 + colsum.
// k-PERMUTED fragment order: slot j of lane (q,m) = Hc[kg*32 + 4*j + q][cg*16+m].
// (Permutation applied identically to the A-side bit fragments -> contraction
// result unchanged; chosen so __ballot words slice directly into bytes.)
__global__ __launch_bounds__(256) void hc_pack_kernel(
    const float* __restrict__ Hc, unsigned short* __restrict__ BP,
    float* __restrict__ R) {
  __shared__ float tile[64][65];
  __shared__ float red[4][64];
  int bk = blockIdx.x >> 2;   // 64 tiles along M (k)
  int bc = blockIdx.x & 3;    // 4 tiles along D (col)
  int k0 = bk * 64, col0 = bc * 64;
  int t = threadIdx.x;
  int lane = t & 63, wv = t >> 6;
  int m = lane & 15, q = lane >> 4;
  float colsum = 0.0f;
#pragma unroll
  for (int i = 0; i < 16; ++i) {
    int e = t + 256 * i;
    int kk = e >> 6, cc = e & 63;
    float v = Hc[(size_t)(k0 + kk) * D_ + col0 + cc];
    tile[kk][cc] = v;
    colsum += v;
  }
  red[wv][t & 63] = colsum;
  __syncthreads();
  if (t < 64)
    atomicAdd(&R[col0 + t], red[0][t] + red[1][t] + red[2][t] + red[3][t]);
#pragma unroll
  for (int t8 = 0; t8 < 2; ++t8) {
    int tile_id = t8 * 4 + wv;
    int sub = tile_id >> 2, g = tile_id & 3;
    int kgg = bk * 2 + sub;
    int cgg = bc * 4 + g;
    short8 v8;
#pragma unroll
    for (int j = 0; j < 8; ++j)
      v8[j] = (short)f2bf(tile[sub * 32 + 4 * j + q][g * 16 + m]);  // permuted k
    *(short8*)(BP + ((size_t)(kgg * 16 + cgg) * 64 + lane) * 8) = v8;
  }
}

// ---------------------------------------------------------------------------
// Prep 3: Wt [O,D] fp32 -> WtP fragment-major bf16, STANDARD k-order
// (epilogue O-GEMM's A side comes from attn LDS in standard order).
__global__ __launch_bounds__(256) void wt_pack_kernel(
    const float* __restrict__ Wt, unsigned short* __restrict__ WtP) {
  int t = blockIdx.x * 256 + threadIdx.x;    // 0..8191
  int lane = t & 63, cg = (t >> 6) & 15, kg = t >> 10;
  int m = lane & 15, q = lane >> 4;
  const float* src = Wt + (size_t)(cg * 16 + m) * D_ + kg * 32 + q * 8;
  float4 w0 = *(const float4*)src, w1 = *(const float4*)(src + 4);
  short8 v8;
  v8[0] = (short)f2bf(w0.x); v8[1] = (short)f2bf(w0.y);
  v8[2] = (short)f2bf(w0.z); v8[3] = (short)f2bf(w0.w);
  v8[4] = (short)f2bf(w1.x); v8[5] = (short)f2bf(w1.y);
  v8[6] = (short)f2bf(w1.z); v8[7] = (short)f2bf(w1.w);
  *(short8*)(WtP + (size_t)t * 8) = v8;
}

// ---------------------------------------------------------------------------
// A-fragment from 8 bits (permuted order): slot j = bit_j ? (t*u8[j] - 1) : 0.
// u8[j] = u[kg*32 + 4*j + q] supplied by caller. bf16 0x0000 = exact +0.
__device__ __forceinline__ short8 frag_from(uint32_t bits, float t,
                                            const float u8[8]) {
  union { short8 s; uint32_t u[4]; } r;
#pragma unroll
  for (int p = 0; p < 4; ++p) {
    float cl = fmaf(t, u8[2 * p], -1.0f);
    float ch = fmaf(t, u8[2 * p + 1], -1.0f);
    uint32_t mlo = 0u - ((bits >> (2 * p)) & 1u);      // 0 or ~0
    uint32_t mhi = 0u - ((bits >> (2 * p + 1)) & 1u);
    r.u[p] = cvtpk(cl, ch) & ((mlo & 0x0000FFFFu) | (mhi & 0xFFFF0000u));
  }
  return r.s;
}

// ---------------------------------------------------------------------------
// MEGA: one kernel = pack bits (adj read once, row-contiguous) + GEMM + epilogue.
// Block = 64 rows x 256 cols x full K, 1024 thr = 16 waves. Grid = N/64 = 256
// -> exactly 1 block/CU (LDS ~116 KB caps blocks/CU at 1 regardless of VGPR).
// launch_bounds(1024, 2): R12's (1024,4) capped VGPR at 128 -> acc spill,
// 197 MB scratch WRITE_SIZE (rocprof). At 2 waves/EU declared the allocator
// gets 256 VGPRs; real occupancy is unchanged (LDS-bound at 16 waves/CU).
// Phase 1: wave w streams rows 4w..4w+3 (float4/lane contiguous, depth-1 chunk
//   prefetch); __ballot packs bits; bit l of u64 word (r, chunk*4+c) =
//   adj[r][chunk*256+4l+c]; byte t = kstep kg=chunk*8+t, quad q=c (matches
//   BP's 4j+q permutation). Exact row denoms reduced in-wave -> registers.
// Phase 2: 4 row-tiles x 4 colq x ksub K-quarter; bits+u from LDS, B from BP
//   (L2) with depth-1 register prefetch; barrier-free 32 iters.
// Phase 3: LDS fp32 atomic combine (4 adds/addr), attn=(C+R)/(L+M)+Hf ->
//   LDS bf16 (overlays bits+u), O-GEMM vs WtP, relu, out.
__global__ __launch_bounds__(1024, 2) void mega_kernel(
    const float* __restrict__ adj, const unsigned short* __restrict__ BP,
    const float* __restrict__ tv, const float* __restrict__ uv,
    const float* __restrict__ Rv, const float* __restrict__ Hf,
    const unsigned short* __restrict__ WtP, const float* __restrict__ bt,
    float* __restrict__ out) {
  union SM {
    struct {
      unsigned long long bt64[64][65];  // 33.3 KB  (+1 u64 pad per row)
      float u[M_];                      // 16 KB
    } s;
    unsigned short attn[64][264];       // 33.8 KB (aliases bits after K loop)
  };
  __shared__ SM sm;
  __shared__ float part[64][260];       // 66.6 KB fp32 C accumulator

  int tid = threadIdx.x;
  int w = tid >> 6, lane = tid & 63;
  int q = lane >> 4, m = lane & 15;
  int colq = w >> 2, ksub = w & 3;
  int i0 = blockIdx.x * 64;

  // ---- pre-barrier staging (no LDS deps): B prefetch, t's, Rv, adj chunk 0
  const unsigned short* bbase = BP + (size_t)(colq * 4) * 512 + (size_t)lane * 8;
  int kg0 = ksub * 32;
  short8 curB[4];
#pragma unroll
  for (int n = 0; n < 4; ++n)
    curB[n] = *(const short8*)(bbase + ((size_t)kg0 * 16 + n) * 512);
  float t0 = tv[i0 + m], t1 = tv[i0 + 16 + m];
  float t2 = tv[i0 + 32 + m], t3 = tv[i0 + 48 + m];
  float4 rvv = *(const float4*)(Rv + lane * 4);

  int r0 = w * 4;                                // phase-1 rows of this wave
  const float* ar = adj + (size_t)(i0 + r0) * M_ + lane * 4;
  float tva = tv[i0 + r0], tvb = tv[i0 + r0 + 1];
  float tvc = tv[i0 + r0 + 2], tvd = tv[i0 + r0 + 3];
  float4 v0 = *(const float4*)(ar);
  float4 v1 = *(const float4*)(ar + M_);
  float4 v2 = *(const float4*)(ar + 2 * M_);
  float4 v3 = *(const float4*)(ar + 3 * M_);

  for (int i = tid; i < M_; i += 1024) sm.s.u[i] = uv[i];
  {
    float* pz = &part[0][0];
    for (int i = tid; i < 64 * 260; i += 1024) pz[i] = 0.0f;
  }
  __syncthreads();  // u + part-zero ready

  // ---- Phase 1: pack bits + denominators
  float su0 = 0.f, sc0 = 0.f, su1 = 0.f, sc1 = 0.f;
  float su2 = 0.f, sc2 = 0.f, su3 = 0.f, sc3 = 0.f;
  const float4* u4 = (const float4*)sm.s.u;
#pragma unroll 1
  for (int chunk = 0; chunk < 16; ++chunk) {
    int nx = (chunk + 1 < 16) ? (chunk + 1) * 256 : 0;   // wrap: harmless reload
    float4 n0 = *(const float4*)(ar + nx);
    float4 n1 = *(const float4*)(ar + nx + M_);
    float4 n2 = *(const float4*)(ar + nx + 2 * M_);
    float4 n3 = *(const float4*)(ar + nx + 3 * M_);
    float4 uu = u4[chunk * 64 + lane];

    unsigned long long b00 = __ballot(v0.x != 0.f), b01 = __ballot(v0.y != 0.f);
    unsigned long long b02 = __ballot(v0.z != 0.f), b03 = __ballot(v0.w != 0.f);
    unsigned long long b10 = __ballot(v1.x != 0.f), b11 = __ballot(v1.y != 0.f);
    unsigned long long b12 = __ballot(v1.z != 0.f), b13 = __ballot(v1.w != 0.f);
    unsigned long long b20 = __ballot(v2.x != 0.f), b21 = __ballot(v2.y != 0.f);
    unsigned long long b22 = __ballot(v2.z != 0.f), b23 = __ballot(v2.w != 0.f);
    unsigned long long b30 = __ballot(v3.x != 0.f), b31 = __ballot(v3.y != 0.f);
    unsigned long long b32 = __ballot(v3.z != 0.f), b33 = __ballot(v3.w != 0.f);
    su0 += v0.x * uu.x + v0.y * uu.y + v0.z * uu.z + v0.w * uu.w;
    sc0 += (v0.x + v0.y) + (v0.z + v0.w);
    su1 += v1.x * uu.x + v1.y * uu.y + v1.z * uu.z + v1.w * uu.w;
    sc1 += (v1.x + v1.y) + (v1.z + v1.w);
    su2 += v2.x * uu.x + v2.y * uu.y + v2.z * uu.z + v2.w * uu.w;
    sc2 += (v2.x + v2.y) + (v2.z + v2.w);
    su3 += v3.x * uu.x + v3.y * uu.y + v3.z * uu.z + v3.w * uu.w;
    sc3 += (v3.x + v3.y) + (v3.z + v3.w);

    // 16 wave-uniform u64s -> lanes 0..15 via select tree (rr = lane>>2, c = lane&3)
#define SELC(a, b, c_, d) ((lane & 2) ? ((lane & 1) ? (d) : (c_)) : ((lane & 1) ? (b) : (a)))
    unsigned long long rs0 = SELC(b00, b01, b02, b03);
    unsigned long long rs1 = SELC(b10, b11, b12, b13);
    unsigned long long rs2 = SELC(b20, b21, b22, b23);
    unsigned long long rs3 = SELC(b30, b31, b32, b33);
#undef SELC
    unsigned long long val =
        (lane & 8) ? ((lane & 4) ? rs3 : rs2) : ((lane & 4) ? rs1 : rs0);
    if (lane < 16)
      sm.s.bt64[r0 + (lane >> 2)][chunk * 4 + (lane & 3)] = val;

    v0 = n0; v1 = n1; v2 = n2; v3 = n3;
  }
  // in-wave reduce -> wave-uniform denominators for rows r0..r0+3
#pragma unroll
  for (int off = 32; off > 0; off >>= 1) {
    su0 += __shfl_xor(su0, off); sc0 += __shfl_xor(sc0, off);
    su1 += __shfl_xor(su1, off); sc1 += __shfl_xor(sc1, off);
    su2 += __shfl_xor(su2, off); sc2 += __shfl_xor(sc2, off);
    su3 += __shfl_xor(su3, off); sc3 += __shfl_xor(sc3, off);
  }
  float invL0 = 1.0f / (tva * su0 - sc0 + (float)M_);
  float invL1 = 1.0f / (tvb * su1 - sc1 + (float)M_);
  float invL2 = 1.0f / (tvc * su2 - sc2 + (float)M_);
  float invL3 = 1.0f / (tvd * su3 - sc3 + (float)M_);
  __syncthreads();  // all bits ready

  // ---- Phase 2: barrier-free K loop (32 ksteps of this wave's K quarter)
  const uint32_t* bt32 = (const uint32_t*)&sm.s.bt64[0][0];   // row stride 130
  f32x4 acc[4][4];
#pragma unroll
  for (int s = 0; s < 4; ++s)
#pragma unroll
    for (int n = 0; n < 4; ++n) acc[s][n] = (f32x4){0.f, 0.f, 0.f, 0.f};
  uint32_t w0 = 0, w1 = 0, w2 = 0, w3 = 0;

#pragma unroll 4
  for (int it = 0; it < 32; ++it) {
    int kg = kg0 + it;
    int kn = (it + 1 < 32) ? kg + 1 : kg0;   // wrap: harmless reload
    short8 nB[4];
#pragma unroll
    for (int n = 0; n < 4; ++n)
      nB[n] = *(const short8*)(bbase + ((size_t)kn * 16 + n) * 512);
    if ((it & 3) == 0) {                      // one u32 covers 4 ksteps
      int widx = (kg >> 3) * 8 + 2 * q + ((kg & 7) >> 2);
      w0 = bt32[(size_t)m * 130 + widx];
      w1 = bt32[(size_t)(16 + m) * 130 + widx];
      w2 = bt32[(size_t)(32 + m) * 130 + widx];
      w3 = bt32[(size_t)(48 + m) * 130 + widx];
    }
    int sh = (kg & 3) * 8;
    float u8[8];
    const float* up = &sm.s.u[kg * 32 + q];
#pragma unroll
    for (int j = 0; j < 8; ++j) u8[j] = up[4 * j];
    short8 af0 = frag_from((w0 >> sh) & 0xffu, t0, u8);
    short8 af1 = frag_from((w1 >> sh) & 0xffu, t1, u8);
    short8 af2 = frag_from((w2 >> sh) & 0xffu, t2, u8);
    short8 af3 = frag_from((w3 >> sh) & 0xffu, t3, u8);
#pragma unroll
    for (int n = 0; n < 4; ++n) {
      acc[0][n] = __builtin_amdgcn_mfma_f32_16x16x32_bf16(af0, curB[n], acc[0][n], 0, 0, 0);
      acc[1][n] = __builtin_amdgcn_mfma_f32_16x16x32_bf16(af1, curB[n], acc[1][n], 0, 0, 0);
      acc[2][n] = __builtin_amdgcn_mfma_f32_16x16x32_bf16(af2, curB[n], acc[2][n], 0, 0, 0);
      acc[3][n] = __builtin_amdgcn_mfma_f32_16x16x32_bf16(af3, curB[n], acc[3][n], 0, 0, 0);
    }
#pragma unroll
    for (int n = 0; n < 4; ++n) curB[n] = nB[n];
  }

  // ---- Phase 3: combine K-quarter partials in LDS (4 adds/address)
#pragma unroll
  for (int s = 0; s < 4; ++s)
#pragma unroll
    for (int n = 0; n < 4; ++n) {
      int col = colq * 64 + n * 16 + m;
#pragma unroll
      for (int r = 0; r < 4; ++r)
        atomicAdd(&part[s * 16 + q * 4 + r][col], acc[s][n][r]);  // C/D: row=(lane>>4)*4+reg
    }
  __syncthreads();

  // attn = (C + R)/(L + M) + Hf -> bf16 LDS (overlays bits+u, both dead)
#pragma unroll
  for (int rr = 0; rr < 4; ++rr) {
    int r = r0 + rr;
    float invL = rr == 0 ? invL0 : rr == 1 ? invL1 : rr == 2 ? invL2 : invL3;
    float4 pv = *(const float4*)&part[r][lane * 4];
    float4 hv = *(const float4*)(Hf + (size_t)(i0 + r) * D_ + lane * 4);
    float a0 = fmaf(pv.x + rvv.x, invL, hv.x);
    float a1 = fmaf(pv.y + rvv.y, invL, hv.y);
    float a2 = fmaf(pv.z + rvv.z, invL, hv.z);
    float a3 = fmaf(pv.w + rvv.w, invL, hv.w);
    *(uint32_t*)&sm.attn[r][lane * 4] = cvtpk(a0, a1);
    *(uint32_t*)&sm.attn[r][lane * 4 + 2] = cvtpk(a2, a3);
  }
  __syncthreads();

  // O-GEMM: out = relu(attn @ Wt^T + bt). 16 waves = 4 rtiles x 4 col-64s.
  int rtile = w & 3, c64 = w >> 2;
  f32x4 facc[4];
#pragma unroll
  for (int n = 0; n < 4; ++n) facc[n] = (f32x4){0.f, 0.f, 0.f, 0.f};
#pragma unroll
  for (int kf = 0; kf < 8; ++kf) {
    short8 af = *(const short8*)&sm.attn[rtile * 16 + m][kf * 32 + q * 8];
#pragma unroll
    for (int n = 0; n < 4; ++n) {
      int cg = c64 * 4 + n;
      short8 bf = *(const short8*)(WtP + ((size_t)(kf * 16 + cg) * 64 + lane) * 8);
      facc[n] = __builtin_amdgcn_mfma_f32_16x16x32_bf16(af, bf, facc[n], 0, 0, 0);
    }
  }
#pragma unroll
  for (int n = 0; n < 4; ++n) {
    int col = c64 * 64 + n * 16 + m;
    float b = bt[col];
#pragma unroll
    for (int r = 0; r < 4; ++r) {
      size_t row = (size_t)i0 + rtile * 16 + q * 4 + r;
      out[row * O_ + col] = fmaxf(facc[n][r] + b, 0.0f);
    }
  }
}

// ---------------------------------------------------------------------------
extern "C" void kernel_launch(void* const* d_in, const int* in_sizes, int n_in,
                              void* d_out, int out_size, void* d_ws, size_t ws_size,
                              hipStream_t stream) {
  const float* Hf  = (const float*)d_in[0];  // [N,D]
  const float* Hc  = (const float*)d_in[1];  // [M,D]
  const float* adj = (const float*)d_in[2];  // [N,M]
  const float* wa  = (const float*)d_in[3];  // [2D]
  const float* ba  = (const float*)d_in[4];  // [1]
  const float* Wt  = (const float*)d_in[5];  // [O,D]
  const float* bt  = (const float*)d_in[6];  // [O]
  float* out = (float*)d_out;

  char* ws = (char*)d_ws;
  float* tv = (float*)(ws + WS_T);
  float* uv = (float*)(ws + WS_U);
  float* Rv = (float*)(ws + WS_R);
  unsigned short* WtP = (unsigned short*)(ws + WS_WTP);
  unsigned short* BP  = (unsigned short*)(ws + WS_BP);

  hipMemsetAsync(Rv, 0, D_ * sizeof(float), stream);  // atomic target

  rowdot_exp_kernel<<<N_ / 4, 256, 0, stream>>>(Hf, wa, ba, tv);           // t = exp(sf+ba)
  rowdot_exp_kernel<<<M_ / 4, 256, 0, stream>>>(Hc, wa + D_, nullptr, uv); // u = exp(sc)
  hc_pack_kernel<<<256, 256, 0, stream>>>(Hc, BP, Rv);
  wt_pack_kernel<<<32, 256, 0, stream>>>(Wt, WtP);

  mega_kernel<<<N_ / 64, 1024, 0, stream>>>(adj, BP, tv, uv, Rv, Hf, WtP, bt, out);
}

// Round 14
// 545.560 us; speedup vs baseline: 1.0608x; 1.0605x over previous
//
#include <hip/hip_runtime.h>
#include <hip/hip_bf16.h>
#include <stdint.h>

// Problem constants (fixed by the reference)
#define N_ 16384
#define M_ 4096
#define D_ 256
#define O_ 256

// Workspace layout (bytes), total ~2.3 MB
#define WS_T    0          // float[N]   exp(sf+ba)   64 KB
#define WS_U    65536      // float[M]   exp(sc)      16 KB
#define WS_R    81920      // float[D]   colsum(Hc)    1 KB
#define WS_WTP  98304      // ushort     Wt packed   128 KB
#define WS_BP   229376     // ushort     Hc packed     2 MB

typedef float  f32x4  __attribute__((ext_vector_type(4)));
typedef short  short8 __attribute__((ext_vector_type(8)));

// fp32 -> bf16 (RNE). Inputs are finite so no NaN handling.
__device__ __forceinline__ unsigned short f2bf(float f) {
  uint32_t u = __float_as_uint(f);
  u += 0x7FFFu + ((u >> 16) & 1u);
  return (unsigned short)(u >> 16);
}
// packed pair fp32 -> bf16
__device__ __forceinline__ uint32_t cvtpk(float a, float b) {
  __hip_bfloat162 h = __float22bfloat162_rn(float2{a, b});
  uint32_t u;
  __builtin_memcpy(&u, &h, 4);
  return u;
}

// ---------------------------------------------------------------------------
// Prep 1: per-row dot with weight vector, then exp(dot + bias).
__global__ __launch_bounds__(256) void rowdot_exp_kernel(
    const float* __restrict__ X, const float* __restrict__ w,
    const float* __restrict__ bias, float* __restrict__ outv) {
  int wv = threadIdx.x >> 6, lane = threadIdx.x & 63;
  int row = blockIdx.x * 4 + wv;
  const float4* x4 = (const float4*)(X + (size_t)row * D_);
  const float4* w4 = (const float4*)w;
  float4 xa = x4[lane], wa4 = w4[lane];
  float s = xa.x * wa4.x + xa.y * wa4.y + xa.z * wa4.z + xa.w * wa4.w;
#pragma unroll
  for (int off = 32; off > 0; off >>= 1) s += __shfl_xor(s, off);
  if (lane == 0) outv[row] = expf(s + (bias ? bias[0] : 0.0f));
}

// ---------------------------------------------------------------------------
// Prep 2: Hc [M,D] fp32 -> BP fragment-major bf16 + colsum.
// k-PERMUTED fragment order: slot j of lane (q,m) = Hc[kg*32 + 4*j + q][cg*16+m].
// (Same permutation on the A-side bits -> contraction unchanged; chosen so
// __ballot words slice directly into fragment bytes.)
__global__ __launch_bounds__(256) void hc_pack_kernel(
    const float* __restrict__ Hc, unsigned short* __restrict__ BP,
    float* __restrict__ R) {
  __shared__ float tile[64][65];
  __shared__ float red[4][64];
  int bk = blockIdx.x >> 2;   // 64 tiles along M (k)
  int bc = blockIdx.x & 3;    // 4 tiles along D (col)
  int k0 = bk * 64, col0 = bc * 64;
  int t = threadIdx.x;
  int lane = t & 63, wv = t >> 6;
  int m = lane & 15, q = lane >> 4;
  float colsum = 0.0f;
#pragma unroll
  for (int i = 0; i < 16; ++i) {
    int e = t + 256 * i;
    int kk = e >> 6, cc = e & 63;
    float v = Hc[(size_t)(k0 + kk) * D_ + col0 + cc];
    tile[kk][cc] = v;
    colsum += v;
  }
  red[wv][t & 63] = colsum;
  __syncthreads();
  if (t < 64)
    atomicAdd(&R[col0 + t], red[0][t] + red[1][t] + red[2][t] + red[3][t]);
#pragma unroll
  for (int t8 = 0; t8 < 2; ++t8) {
    int tile_id = t8 * 4 + wv;
    int sub = tile_id >> 2, g = tile_id & 3;
    int kgg = bk * 2 + sub;
    int cgg = bc * 4 + g;
    short8 v8;
#pragma unroll
    for (int j = 0; j < 8; ++j)
      v8[j] = (short)f2bf(tile[sub * 32 + 4 * j + q][g * 16 + m]);  // permuted k
    *(short8*)(BP + ((size_t)(kgg * 16 + cgg) * 64 + lane) * 8) = v8;
  }
}

// ---------------------------------------------------------------------------
// Prep 3: Wt [O,D] fp32 -> WtP fragment-major bf16, STANDARD k-order
// (epilogue O-GEMM's A side comes from attn LDS in standard order).
__global__ __launch_bounds__(256) void wt_pack_kernel(
    const float* __restrict__ Wt, unsigned short* __restrict__ WtP) {
  int t = blockIdx.x * 256 + threadIdx.x;    // 0..8191
  int lane = t & 63, cg = (t >> 6) & 15, kg = t >> 10;
  int m = lane & 15, q = lane >> 4;
  const float* src = Wt + (size_t)(cg * 16 + m) * D_ + kg * 32 + q * 8;
  float4 w0 = *(const float4*)src, w1 = *(const float4*)(src + 4);
  short8 v8;
  v8[0] = (short)f2bf(w0.x); v8[1] = (short)f2bf(w0.y);
  v8[2] = (short)f2bf(w0.z); v8[3] = (short)f2bf(w0.w);
  v8[4] = (short)f2bf(w1.x); v8[5] = (short)f2bf(w1.y);
  v8[6] = (short)f2bf(w1.z); v8[7] = (short)f2bf(w1.w);
  *(short8*)(WtP + (size_t)t * 8) = v8;
}

// ---------------------------------------------------------------------------
// A-fragment from 8 bits (permuted order): slot j = bit_j ? (t*u8[j] - 1) : 0.
// u8 = (ua.x..ua.w, ub.x..ub.w) from the permuted u2 table. bf16 0x0000 = +0.
__device__ __forceinline__ short8 frag_from(uint32_t bits, float t,
                                            float4 ua, float4 ub) {
  float u8[8] = {ua.x, ua.y, ua.z, ua.w, ub.x, ub.y, ub.z, ub.w};
  union { short8 s; uint32_t u[4]; } r;
#pragma unroll
  for (int p = 0; p < 4; ++p) {
    float cl = fmaf(t, u8[2 * p], -1.0f);
    float ch = fmaf(t, u8[2 * p + 1], -1.0f);
    uint32_t mlo = 0u - ((bits >> (2 * p)) & 1u);      // 0 or ~0
    uint32_t mhi = 0u - ((bits >> (2 * p + 1)) & 1u);
    r.u[p] = cvtpk(cl, ch) & ((mlo & 0x0000FFFFu) | (mhi & 0xFFFF0000u));
  }
  return r.s;
}

// ---------------------------------------------------------------------------
// MEGA v2: one kernel = pack bits + GEMM + epilogue, REGISTER-FIT edition.
// HW law (R12/R13 post-mortem): a 1024-thr block = 16 co-resident waves ->
// <=128 regs/wave TOTAL (arch+AGPR), launch_bounds can't lift it. R12/13 used
// acc[4][4] (64 AGPR) + 64 arch = 128 -> catastrophic scratch spill (197 MB
// WRITE_SIZE). Fix: acc[4][2] (32 AGPR), 16 waves = 8 col-pairs x 2 K-halves.
// Each BP fragment still read exactly once per block (8cq x 2cg = 16 cg,
// 2ks x 64 = 128 kg). ~100 regs total -> no spill.
// Phase 1: wave w streams rows 4w..4w+3 row-contiguously (float4/lane,
//   depth-1 chunk prefetch); __ballot packs bits (u64 word (r, chunk*4+c),
//   byte t = kstep, matching BP's 4j+q permutation); exact row denominators
//   reduced in-wave into registers.
// Phase 2: barrier-free 64-iter K-half loop; bits + permuted-u (2x ds_read_b128)
//   from LDS; B depth-1 register prefetch; 8 MFMA/iter.
// Phase 3: LDS fp32 atomic combine (2 adds/addr), attn=(C+R)/(L+M)+Hf ->
//   LDS bf16 (overlays bits+u), O-GEMM vs WtP, relu, out.
// Grid = N/64 = 256 -> 1 block/CU (LDS ~132 KB).
__global__ __launch_bounds__(1024) void mega_kernel(
    const float* __restrict__ adj, const unsigned short* __restrict__ BP,
    const float* __restrict__ tv, const float* __restrict__ uv,
    const float* __restrict__ Rv, const float* __restrict__ Hf,
    const unsigned short* __restrict__ WtP, const float* __restrict__ bt,
    float* __restrict__ out) {
  union SM {
    struct {
      unsigned long long bt64[64][65];  // 33.3 KB  (+1 u64 pad per row)
      float u[M_];                      // 16 KB  natural order (phase 1)
      float u2[M_];                     // 16 KB  permuted order (phase 2)
    } s;
    unsigned short attn[64][264];       // 33.8 KB (aliases bt64/u after K loop)
  };
  __shared__ SM sm;
  __shared__ float part[64][260];       // 66.6 KB fp32 C accumulator

  int tid = threadIdx.x;
  int w = tid >> 6, lane = tid & 63;
  int q = lane >> 4, m = lane & 15;
  int colq = w >> 1, ksub = w & 1;      // 8 col-pairs x 2 K-halves
  int i0 = blockIdx.x * 64;

  // ---- pre-barrier staging (no LDS deps): B prefetch, t's, Rv, adj chunk 0
  const unsigned short* bbase = BP + (size_t)(colq * 2) * 512 + (size_t)lane * 8;
  int kg0 = ksub * 64;
  short8 curB[2];
  curB[0] = *(const short8*)(bbase + (size_t)kg0 * 8192);
  curB[1] = *(const short8*)(bbase + (size_t)kg0 * 8192 + 512);
  float t0 = tv[i0 + m], t1 = tv[i0 + 16 + m];
  float t2 = tv[i0 + 32 + m], t3 = tv[i0 + 48 + m];
  float4 rvv = *(const float4*)(Rv + lane * 4);

  int r0 = w * 4;                                // phase-1 rows of this wave
  const float* ar = adj + (size_t)(i0 + r0) * M_ + lane * 4;
  float tva = tv[i0 + r0], tvb = tv[i0 + r0 + 1];
  float tvc = tv[i0 + r0 + 2], tvd = tv[i0 + r0 + 3];
  float4 v0 = *(const float4*)(ar);
  float4 v1 = *(const float4*)(ar + M_);
  float4 v2 = *(const float4*)(ar + 2 * M_);
  float4 v3 = *(const float4*)(ar + 3 * M_);

  for (int i = tid; i < M_; i += 1024) sm.s.u[i] = uv[i];
  for (int i = tid; i < M_; i += 1024) {
    int kg = i >> 5, rem = i & 31, qq = rem >> 3, j = rem & 7;
    sm.s.u2[i] = uv[kg * 32 + 4 * j + qq];       // permuted fragment order
  }
  {
    float* pz = &part[0][0];
    for (int i = tid; i < 64 * 260; i += 1024) pz[i] = 0.0f;
  }
  __syncthreads();  // u, u2, part-zero ready

  // ---- Phase 1: pack bits + denominators (row-contiguous adj, read once)
  float su0 = 0.f, sc0 = 0.f, su1 = 0.f, sc1 = 0.f;
  float su2 = 0.f, sc2 = 0.f, su3 = 0.f, sc3 = 0.f;
  const float4* u4 = (const float4*)sm.s.u;
#pragma unroll 1
  for (int chunk = 0; chunk < 16; ++chunk) {
    int nx = (chunk + 1 < 16) ? (chunk + 1) * 256 : 0;   // wrap: harmless reload
    float4 n0 = *(const float4*)(ar + nx);
    float4 n1 = *(const float4*)(ar + nx + M_);
    float4 n2 = *(const float4*)(ar + nx + 2 * M_);
    float4 n3 = *(const float4*)(ar + nx + 3 * M_);
    float4 uu = u4[chunk * 64 + lane];

    unsigned long long b00 = __ballot(v0.x != 0.f), b01 = __ballot(v0.y != 0.f);
    unsigned long long b02 = __ballot(v0.z != 0.f), b03 = __ballot(v0.w != 0.f);
    unsigned long long b10 = __ballot(v1.x != 0.f), b11 = __ballot(v1.y != 0.f);
    unsigned long long b12 = __ballot(v1.z != 0.f), b13 = __ballot(v1.w != 0.f);
    unsigned long long b20 = __ballot(v2.x != 0.f), b21 = __ballot(v2.y != 0.f);
    unsigned long long b22 = __ballot(v2.z != 0.f), b23 = __ballot(v2.w != 0.f);
    unsigned long long b30 = __ballot(v3.x != 0.f), b31 = __ballot(v3.y != 0.f);
    unsigned long long b32 = __ballot(v3.z != 0.f), b33 = __ballot(v3.w != 0.f);
    su0 += v0.x * uu.x + v0.y * uu.y + v0.z * uu.z + v0.w * uu.w;
    sc0 += (v0.x + v0.y) + (v0.z + v0.w);
    su1 += v1.x * uu.x + v1.y * uu.y + v1.z * uu.z + v1.w * uu.w;
    sc1 += (v1.x + v1.y) + (v1.z + v1.w);
    su2 += v2.x * uu.x + v2.y * uu.y + v2.z * uu.z + v2.w * uu.w;
    sc2 += (v2.x + v2.y) + (v2.z + v2.w);
    su3 += v3.x * uu.x + v3.y * uu.y + v3.z * uu.z + v3.w * uu.w;
    sc3 += (v3.x + v3.y) + (v3.z + v3.w);

    // 16 wave-uniform u64s -> lanes 0..15 via select tree
#define SELC(a, b, c_, d) ((lane & 2) ? ((lane & 1) ? (d) : (c_)) : ((lane & 1) ? (b) : (a)))
    unsigned long long rs0 = SELC(b00, b01, b02, b03);
    unsigned long long rs1 = SELC(b10, b11, b12, b13);
    unsigned long long rs2 = SELC(b20, b21, b22, b23);
    unsigned long long rs3 = SELC(b30, b31, b32, b33);
#undef SELC
    unsigned long long val =
        (lane & 8) ? ((lane & 4) ? rs3 : rs2) : ((lane & 4) ? rs1 : rs0);
    if (lane < 16)
      sm.s.bt64[r0 + (lane >> 2)][chunk * 4 + (lane & 3)] = val;

    v0 = n0; v1 = n1; v2 = n2; v3 = n3;
  }
  // in-wave reduce -> wave-uniform denominators for rows r0..r0+3
#pragma unroll
  for (int off = 32; off > 0; off >>= 1) {
    su0 += __shfl_xor(su0, off); sc0 += __shfl_xor(sc0, off);
    su1 += __shfl_xor(su1, off); sc1 += __shfl_xor(sc1, off);
    su2 += __shfl_xor(su2, off); sc2 += __shfl_xor(sc2, off);
    su3 += __shfl_xor(su3, off); sc3 += __shfl_xor(sc3, off);
  }
  float invL0 = 1.0f / (tva * su0 - sc0 + (float)M_);
  float invL1 = 1.0f / (tvb * su1 - sc1 + (float)M_);
  float invL2 = 1.0f / (tvc * su2 - sc2 + (float)M_);
  float invL3 = 1.0f / (tvd * su3 - sc3 + (float)M_);
  __syncthreads();  // all bits ready

  // ---- Phase 2: barrier-free K-half loop (64 ksteps), acc[4][2] = 32 AGPR
  const uint32_t* bt32 = (const uint32_t*)&sm.s.bt64[0][0];   // row stride 130
  f32x4 acc[4][2];
#pragma unroll
  for (int s = 0; s < 4; ++s) {
    acc[s][0] = (f32x4){0.f, 0.f, 0.f, 0.f};
    acc[s][1] = (f32x4){0.f, 0.f, 0.f, 0.f};
  }
  uint32_t w0 = 0, w1 = 0, w2 = 0, w3 = 0;

#pragma unroll 4
  for (int it = 0; it < 64; ++it) {
    int kg = kg0 + it;
    int kn = (it + 1 < 64) ? kg + 1 : kg0;   // wrap: harmless reload
    short8 nB0 = *(const short8*)(bbase + (size_t)kn * 8192);
    short8 nB1 = *(const short8*)(bbase + (size_t)kn * 8192 + 512);
    if ((it & 3) == 0) {                      // one u32 covers 4 ksteps
      int widx = (kg >> 3) * 8 + 2 * q + ((kg & 7) >> 2);
      w0 = bt32[(size_t)m * 130 + widx];
      w1 = bt32[(size_t)(16 + m) * 130 + widx];
      w2 = bt32[(size_t)(32 + m) * 130 + widx];
      w3 = bt32[(size_t)(48 + m) * 130 + widx];
    }
    int sh = (kg & 3) * 8;
    const float* u2p = &sm.s.u2[kg * 32 + q * 8];
    float4 ua = *(const float4*)(u2p);
    float4 ub = *(const float4*)(u2p + 4);
    short8 af0 = frag_from((w0 >> sh) & 0xffu, t0, ua, ub);
    short8 af1 = frag_from((w1 >> sh) & 0xffu, t1, ua, ub);
    short8 af2 = frag_from((w2 >> sh) & 0xffu, t2, ua, ub);
    short8 af3 = frag_from((w3 >> sh) & 0xffu, t3, ua, ub);
    acc[0][0] = __builtin_amdgcn_mfma_f32_16x16x32_bf16(af0, curB[0], acc[0][0], 0, 0, 0);
    acc[1][0] = __builtin_amdgcn_mfma_f32_16x16x32_bf16(af1, curB[0], acc[1][0], 0, 0, 0);
    acc[2][0] = __builtin_amdgcn_mfma_f32_16x16x32_bf16(af2, curB[0], acc[2][0], 0, 0, 0);
    acc[3][0] = __builtin_amdgcn_mfma_f32_16x16x32_bf16(af3, curB[0], acc[3][0], 0, 0, 0);
    acc[0][1] = __builtin_amdgcn_mfma_f32_16x16x32_bf16(af0, curB[1], acc[0][1], 0, 0, 0);
    acc[1][1] = __builtin_amdgcn_mfma_f32_16x16x32_bf16(af1, curB[1], acc[1][1], 0, 0, 0);
    acc[2][1] = __builtin_amdgcn_mfma_f32_16x16x32_bf16(af2, curB[1], acc[2][1], 0, 0, 0);
    acc[3][1] = __builtin_amdgcn_mfma_f32_16x16x32_bf16(af3, curB[1], acc[3][1], 0, 0, 0);
    curB[0] = nB0; curB[1] = nB1;
  }

  // ---- Phase 3: combine K-half partials in LDS (2 adds/address)
#pragma unroll
  for (int s = 0; s < 4; ++s)
#pragma unroll
    for (int n = 0; n < 2; ++n) {
      int col = colq * 32 + n * 16 + m;
#pragma unroll
      for (int r = 0; r < 4; ++r)
        atomicAdd(&part[s * 16 + q * 4 + r][col], acc[s][n][r]);  // C/D: row=(lane>>4)*4+reg
    }
  __syncthreads();

  // attn = (C + R)/(L + M) + Hf -> bf16 LDS (overlays bits+u, both dead)
#pragma unroll
  for (int rr = 0; rr < 4; ++rr) {
    int r = r0 + rr;
    float invL = rr == 0 ? invL0 : rr == 1 ? invL1 : rr == 2 ? invL2 : invL3;
    float4 pv = *(const float4*)&part[r][lane * 4];
    float4 hv = *(const float4*)(Hf + (size_t)(i0 + r) * D_ + lane * 4);
    float a0 = fmaf(pv.x + rvv.x, invL, hv.x);
    float a1 = fmaf(pv.y + rvv.y, invL, hv.y);
    float a2 = fmaf(pv.z + rvv.z, invL, hv.z);
    float a3 = fmaf(pv.w + rvv.w, invL, hv.w);
    *(uint32_t*)&sm.attn[r][lane * 4] = cvtpk(a0, a1);
    *(uint32_t*)&sm.attn[r][lane * 4 + 2] = cvtpk(a2, a3);
  }
  __syncthreads();

  // O-GEMM: out = relu(attn @ Wt^T + bt). 16 waves = 4 rtiles x 4 col-64s.
  int rtile = w & 3, c64 = w >> 2;
  f32x4 facc[4];
#pragma unroll
  for (int n = 0; n < 4; ++n) facc[n] = (f32x4){0.f, 0.f, 0.f, 0.f};
#pragma unroll
  for (int kf = 0; kf < 8; ++kf) {
    short8 af = *(const short8*)&sm.attn[rtile * 16 + m][kf * 32 + q * 8];
#pragma unroll
    for (int n = 0; n < 4; ++n) {
      int cg = c64 * 4 + n;
      short8 bf = *(const short8*)(WtP + ((size_t)(kf * 16 + cg) * 64 + lane) * 8);
      facc[n] = __builtin_amdgcn_mfma_f32_16x16x32_bf16(af, bf, facc[n], 0, 0, 0);
    }
  }
#pragma unroll
  for (int n = 0; n < 4; ++n) {
    int col = c64 * 64 + n * 16 + m;
    float b = bt[col];
#pragma unroll
    for (int r = 0; r < 4; ++r) {
      size_t row = (size_t)i0 + rtile * 16 + q * 4 + r;
      out[row * O_ + col] = fmaxf(facc[n][r] + b, 0.0f);
    }
  }
}

// ---------------------------------------------------------------------------
extern "C" void kernel_launch(void* const* d_in, const int* in_sizes, int n_in,
                              void* d_out, int out_size, void* d_ws, size_t ws_size,
                              hipStream_t stream) {
  const float* Hf  = (const float*)d_in[0];  // [N,D]
  const float* Hc  = (const float*)d_in[1];  // [M,D]
  const float* adj = (const float*)d_in[2];  // [N,M]
  const float* wa  = (const float*)d_in[3];  // [2D]
  const float* ba  = (const float*)d_in[4];  // [1]
  const float* Wt  = (const float*)d_in[5];  // [O,D]
  const float* bt  = (const float*)d_in[6];  // [O]
  float* out = (float*)d_out;

  char* ws = (char*)d_ws;
  float* tv = (float*)(ws + WS_T);
  float* uv = (float*)(ws + WS_U);
  float* Rv = (float*)(ws + WS_R);
  unsigned short* WtP = (unsigned short*)(ws + WS_WTP);
  unsigned short* BP  = (unsigned short*)(ws + WS_BP);

  hipMemsetAsync(Rv, 0, D_ * sizeof(float), stream);  // atomic target

  rowdot_exp_kernel<<<N_ / 4, 256, 0, stream>>>(Hf, wa, ba, tv);           // t = exp(sf+ba)
  rowdot_exp_kernel<<<M_ / 4, 256, 0, stream>>>(Hc, wa + D_, nullptr, uv); // u = exp(sc)
  hc_pack_kernel<<<256, 256, 0, stream>>>(Hc, BP, Rv);
  wt_pack_kernel<<<32, 256, 0, stream>>>(Wt, WtP);

  mega_kernel<<<N_ / 64, 1024, 0, stream>>>(adj, BP, tv, uv, Rv, Hf, WtP, bt, out);
}